// Round 2
// baseline (550.138 us; speedup 1.0000x reference)
//
#include <hip/hip_runtime.h>
#include <hip/hip_bf16.h>

// ---------------------------------------------------------------------------
// InterpretableMultiHeadAttention  (B=8, S=1024, D=1024, H=16, dk=64)
//   outputs [B,S,D] fp32 ; attn [B,Sq,H,Sk] fp32  (concatenated in d_out)
// Pipeline:
//   1) proj_qk : qs = (q @ Wq^T)/8, ks = k @ Wk^T   (bf16, [b,s,(h,e)] layout)
//   2) proj_v  : vsT = (v @ Wv^T)^T                 (bf16, [b][e][t] layout)
//   3) attn    : 2-pass softmax (sum of exp, no max needed), writes attn fp32,
//                PV via MFMA, heads -> ws (bf16)
//   4) out     : outputs = mean_h(heads) @ Wo^T     (VALU)
// All f32->bf16 conversions are round-to-nearest-even (truncation's coherent
// -0.2%/op bias compounded to ~-1.2% on scores -> 6e-3 attn error; RNE kills it).
// ---------------------------------------------------------------------------

typedef __attribute__((ext_vector_type(4))) float f32x4;
typedef __attribute__((ext_vector_type(8))) short bf16x8;
typedef __attribute__((ext_vector_type(2))) unsigned int uint2v;

#define MFMA16(a, b, c) __builtin_amdgcn_mfma_f32_16x16x32_bf16((a), (b), (c), 0, 0, 0)

__device__ __forceinline__ unsigned int rne16(float f) {
  unsigned int u = __float_as_uint(f);
  return u + 0x7fffu + ((u >> 16) & 1u);   // round-to-nearest-even in bit 16
}
__device__ __forceinline__ unsigned int pack2bf(float a, float b) {
  return (rne16(a) >> 16) | (rne16(b) & 0xffff0000u);
}
__device__ __forceinline__ short f2bf(float f) {
  return (short)(rne16(f) >> 16);
}
__device__ __forceinline__ float bf2f(short s) {
  return __uint_as_float(((unsigned int)(unsigned short)s) << 16);
}

// ---------------------------------------------------------------------------
// Kernel 1: fused Q/K projection.  A [8192,1024] f32, W [1024,1024] f32 (B^T
// layout, i.e. [out,in]), C [8192,1024] bf16.  grid = (64, 16): y<8 -> Q, else K.
// ---------------------------------------------------------------------------
__global__ __launch_bounds__(256) void proj_qk_kernel(
    const float* __restrict__ qin, const float* __restrict__ kin,
    const float* __restrict__ Wq, const float* __restrict__ Wk,
    __hip_bfloat16* __restrict__ qs, __hip_bfloat16* __restrict__ ks)
{
  const int K = 1024, N = 1024;
  __shared__ short a_lds[128][40];   // padded stride 40 (80B) -> ~2-way banks
  __shared__ short b_lds[128][40];
  const int tid  = threadIdx.x;
  const int lane = tid & 63, wid = tid >> 6;
  const int g = lane >> 4, r = lane & 15;
  const bool isK = blockIdx.y >= 8;
  const float* A = isK ? kin : qin;
  const float* W = isK ? Wk : Wq;
  __hip_bfloat16* C = isK ? ks : qs;
  const float scale = isK ? 1.0f : 0.125f;   // 1/sqrt(dk)=1/8 folded into qs
  const int m0 = blockIdx.x * 128;
  const int n0 = (blockIdx.y & 7) * 128;
  const int wm = (wid >> 1) * 64, wn = (wid & 1) * 64;
  const int lrow = tid >> 3, lcol = (tid & 7) * 4;

  f32x4 acc[4][4];
#pragma unroll
  for (int i = 0; i < 4; ++i)
#pragma unroll
    for (int j = 0; j < 4; ++j) acc[i][j] = (f32x4){0.f, 0.f, 0.f, 0.f};

  for (int k0 = 0; k0 < K; k0 += 32) {
    float4 av[4], wv[4];
#pragma unroll
    for (int p = 0; p < 4; ++p) {
      av[p] = *(const float4*)&A[(m0 + lrow + p * 32) * K + k0 + lcol];
      wv[p] = *(const float4*)&W[(n0 + lrow + p * 32) * K + k0 + lcol];
    }
    __syncthreads();
#pragma unroll
    for (int p = 0; p < 4; ++p) {
      uint2v ua = {pack2bf(av[p].x, av[p].y), pack2bf(av[p].z, av[p].w)};
      uint2v uw = {pack2bf(wv[p].x, wv[p].y), pack2bf(wv[p].z, wv[p].w)};
      *(uint2v*)&a_lds[lrow + p * 32][lcol] = ua;
      *(uint2v*)&b_lds[lrow + p * 32][lcol] = uw;
    }
    __syncthreads();
    bf16x8 af[4], bf[4];
#pragma unroll
    for (int t = 0; t < 4; ++t) {
      af[t] = *(bf16x8*)&a_lds[wm + t * 16 + r][g * 8];
      bf[t] = *(bf16x8*)&b_lds[wn + t * 16 + r][g * 8];
    }
#pragma unroll
    for (int mt = 0; mt < 4; ++mt)
#pragma unroll
      for (int nt = 0; nt < 4; ++nt)
        acc[mt][nt] = MFMA16(af[mt], bf[nt], acc[mt][nt]);
  }

#pragma unroll
  for (int mt = 0; mt < 4; ++mt)
#pragma unroll
    for (int nt = 0; nt < 4; ++nt) {
      const int n = n0 + wn + nt * 16 + r;
#pragma unroll
      for (int j = 0; j < 4; ++j) {
        const int m = m0 + wm + mt * 16 + 4 * g + j;
        C[m * N + n] = __float2bfloat16(acc[mt][nt][j] * scale);
      }
    }
}

// ---------------------------------------------------------------------------
// Kernel 2: V projection, output TRANSPOSED per batch: vsT[b][e][t] bf16.
// M=8192 (b,t), N=64, K=1024.  grid = 64.
// ---------------------------------------------------------------------------
__global__ __launch_bounds__(256) void proj_v_kernel(
    const float* __restrict__ vin, const float* __restrict__ Wv,
    __hip_bfloat16* __restrict__ vsT)
{
  const int K = 1024;
  __shared__ short a_lds[128][40];
  __shared__ short b_lds[64][40];
  const int tid  = threadIdx.x;
  const int lane = tid & 63, wid = tid >> 6;
  const int g = lane >> 4, r = lane & 15;
  const int m0 = blockIdx.x * 128;
  const int wm = wid * 32;
  const int lrow = tid >> 3, lcol = (tid & 7) * 4;

  f32x4 acc[2][4];
#pragma unroll
  for (int i = 0; i < 2; ++i)
#pragma unroll
    for (int j = 0; j < 4; ++j) acc[i][j] = (f32x4){0.f, 0.f, 0.f, 0.f};

  for (int k0 = 0; k0 < K; k0 += 32) {
    float4 av[4], wv2[2];
#pragma unroll
    for (int p = 0; p < 4; ++p)
      av[p] = *(const float4*)&vin[(m0 + lrow + p * 32) * K + k0 + lcol];
#pragma unroll
    for (int p = 0; p < 2; ++p)
      wv2[p] = *(const float4*)&Wv[(lrow + p * 32) * K + k0 + lcol];
    __syncthreads();
#pragma unroll
    for (int p = 0; p < 4; ++p) {
      uint2v ua = {pack2bf(av[p].x, av[p].y), pack2bf(av[p].z, av[p].w)};
      *(uint2v*)&a_lds[lrow + p * 32][lcol] = ua;
    }
#pragma unroll
    for (int p = 0; p < 2; ++p) {
      uint2v uw = {pack2bf(wv2[p].x, wv2[p].y), pack2bf(wv2[p].z, wv2[p].w)};
      *(uint2v*)&b_lds[lrow + p * 32][lcol] = uw;
    }
    __syncthreads();
    bf16x8 af[2], bf[4];
#pragma unroll
    for (int t = 0; t < 2; ++t) af[t] = *(bf16x8*)&a_lds[wm + t * 16 + r][g * 8];
#pragma unroll
    for (int t = 0; t < 4; ++t) bf[t] = *(bf16x8*)&b_lds[t * 16 + r][g * 8];
#pragma unroll
    for (int mt = 0; mt < 2; ++mt)
#pragma unroll
      for (int nt = 0; nt < 4; ++nt)
        acc[mt][nt] = MFMA16(af[mt], bf[nt], acc[mt][nt]);
  }

#pragma unroll
  for (int mt = 0; mt < 2; ++mt)
#pragma unroll
    for (int nt = 0; nt < 4; ++nt) {
      const int e = nt * 16 + r;
#pragma unroll
      for (int j = 0; j < 4; ++j) {
        const int m = m0 + wm + mt * 16 + 4 * g + j;
        const int b = m >> 10, t = m & 1023;
        vsT[b * 65536 + e * 1024 + t] = __float2bfloat16(acc[mt][nt][j]);
      }
    }
}

// ---------------------------------------------------------------------------
// Kernel 3: fused attention.  grid = (S/64=16, H=16, B=8), 4 waves, each wave
// owns 16 query rows.  Pass 1: l = sum(exp(s)) (scores bounded, no max
// needed).  Pass 2: recompute scores, write p = exp(s)/l to attn (fp32),
// stage p as bf16 in per-wave LDS, PV via MFMA.  heads -> bf16 ws.
// ---------------------------------------------------------------------------
__global__ __launch_bounds__(256) void attn_kernel(
    const __hip_bfloat16* __restrict__ qs_, const __hip_bfloat16* __restrict__ ks_,
    const __hip_bfloat16* __restrict__ vsT_, float* __restrict__ attn_out,
    __hip_bfloat16* __restrict__ heads_)
{
  const int S = 1024, H = 16;
  const int tid = threadIdx.x, lane = tid & 63, wid = tid >> 6;
  const int g = lane >> 4, r = lane & 15;
  const int qb = blockIdx.x, h = blockIdx.y, b = blockIdx.z;
  const int bh = b * H + h;
  const int qrow = qb * 64 + wid * 16;
  __shared__ short p_lds[4][16][40];   // per-wave p staging (padded)

  const short* qsp = (const short*)qs_;
  const short* ksp = (const short*)ks_;
  const short* vsp = (const short*)vsT_;
  short* headsp = (short*)heads_;

  const int qidx = (b * S + qrow + r) * 1024 + h * 64;
  const bf16x8 qf0 = *(const bf16x8*)&qsp[qidx + g * 8];
  const bf16x8 qf1 = *(const bf16x8*)&qsp[qidx + 32 + g * 8];
  const int kbase = (b * S + r) * 1024 + h * 64 + g * 8;

  // ---- pass 1: per-row sum of exp(scores) ----
  float ls0 = 0.f, ls1 = 0.f, ls2 = 0.f, ls3 = 0.f;
  for (int t0 = 0; t0 < S; t0 += 16) {
    const bf16x8 kf0 = *(const bf16x8*)&ksp[kbase + t0 * 1024];
    const bf16x8 kf1 = *(const bf16x8*)&ksp[kbase + t0 * 1024 + 32];
    f32x4 s = (f32x4){0.f, 0.f, 0.f, 0.f};
    s = MFMA16(qf0, kf0, s);
    s = MFMA16(qf1, kf1, s);
    ls0 += __expf(s[0]); ls1 += __expf(s[1]);
    ls2 += __expf(s[2]); ls3 += __expf(s[3]);
  }
#pragma unroll
  for (int mk = 1; mk < 16; mk <<= 1) {
    ls0 += __shfl_xor(ls0, mk);
    ls1 += __shfl_xor(ls1, mk);
    ls2 += __shfl_xor(ls2, mk);
    ls3 += __shfl_xor(ls3, mk);
  }
  const float inv0 = 1.f / ls0, inv1 = 1.f / ls1, inv2 = 1.f / ls2, inv3 = 1.f / ls3;

  // ---- pass 2: write attn + PV ----
  f32x4 hacc[4];
#pragma unroll
  for (int i = 0; i < 4; ++i) hacc[i] = (f32x4){0.f, 0.f, 0.f, 0.f};

  int abase[4];
#pragma unroll
  for (int j = 0; j < 4; ++j)
    abase[j] = ((b * S + qrow + 4 * g + j) * H + h) * S + r;
  const int vbase = b * 65536 + r * 1024 + g * 8;

  for (int tc = 0; tc < S; tc += 32) {
#pragma unroll
    for (int sub = 0; sub < 2; ++sub) {
      const int t0 = tc + sub * 16;
      const bf16x8 kf0 = *(const bf16x8*)&ksp[kbase + t0 * 1024];
      const bf16x8 kf1 = *(const bf16x8*)&ksp[kbase + t0 * 1024 + 32];
      f32x4 s = (f32x4){0.f, 0.f, 0.f, 0.f};
      s = MFMA16(qf0, kf0, s);
      s = MFMA16(qf1, kf1, s);
      const float p0 = __expf(s[0]) * inv0;
      const float p1 = __expf(s[1]) * inv1;
      const float p2 = __expf(s[2]) * inv2;
      const float p3 = __expf(s[3]) * inv3;
      attn_out[abase[0] + t0] = p0;
      attn_out[abase[1] + t0] = p1;
      attn_out[abase[2] + t0] = p2;
      attn_out[abase[3] + t0] = p3;
      p_lds[wid][4 * g + 0][sub * 16 + r] = f2bf(p0);
      p_lds[wid][4 * g + 1][sub * 16 + r] = f2bf(p1);
      p_lds[wid][4 * g + 2][sub * 16 + r] = f2bf(p2);
      p_lds[wid][4 * g + 3][sub * 16 + r] = f2bf(p3);
    }
    // per-wave cross-lane LDS hazard: drain DS queue before reading back
    asm volatile("s_waitcnt lgkmcnt(0)" ::: "memory");
    const bf16x8 pa = *(bf16x8*)&p_lds[wid][r][g * 8];
#pragma unroll
    for (int nt = 0; nt < 4; ++nt) {
      const bf16x8 vf = *(const bf16x8*)&vsp[vbase + nt * 16384 + tc];
      hacc[nt] = MFMA16(pa, vf, hacc[nt]);
    }
  }

#pragma unroll
  for (int nt = 0; nt < 4; ++nt)
#pragma unroll
    for (int j = 0; j < 4; ++j)
      headsp[(bh * S + qrow + 4 * g + j) * 64 + nt * 16 + r] =
          f2bf(hacc[nt][j]);
}

// ---------------------------------------------------------------------------
// Kernel 4: outputs = mean_h(heads) @ Wo^T.  grid = 512, 16 rows per block.
// ---------------------------------------------------------------------------
__global__ __launch_bounds__(256) void out_kernel(
    const __hip_bfloat16* __restrict__ heads_, const float* __restrict__ Wo,
    float* __restrict__ out)
{
  __shared__ float hm[16][64];
  const int tid = threadIdx.x;
  const int m0 = blockIdx.x * 16;
  const short* headsp = (const short*)heads_;

  {
    const int row = tid >> 4, e4 = (tid & 15) * 4;
    const int m = m0 + row, b = m >> 10, s = m & 1023;
    float a0 = 0.f, a1 = 0.f, a2 = 0.f, a3 = 0.f;
    for (int hh = 0; hh < 16; ++hh) {
      typedef __attribute__((ext_vector_type(4))) short short4v;
      const short4v hv =
          *(const short4v*)&headsp[((b * 16 + hh) * 1024 + s) * 64 + e4];
      a0 += bf2f(hv[0]); a1 += bf2f(hv[1]); a2 += bf2f(hv[2]); a3 += bf2f(hv[3]);
    }
    const float sc = 1.f / 16.f;
    hm[row][e4 + 0] = a0 * sc; hm[row][e4 + 1] = a1 * sc;
    hm[row][e4 + 2] = a2 * sc; hm[row][e4 + 3] = a3 * sc;
  }
  __syncthreads();

  for (int c = 0; c < 4; ++c) {
    const int d = c * 256 + tid;
    float4 wo4[16];
#pragma unroll
    for (int i = 0; i < 16; ++i) wo4[i] = *(const float4*)&Wo[d * 64 + i * 4];
    for (int row = 0; row < 16; ++row) {
      float a = 0.f;
#pragma unroll
      for (int i = 0; i < 16; ++i) {
        const float4 h4 = *(const float4*)&hm[row][i * 4];
        a += h4.x * wo4[i].x + h4.y * wo4[i].y + h4.z * wo4[i].z + h4.w * wo4[i].w;
      }
      out[(m0 + row) * 1024 + d] = a;
    }
  }
}

// ---------------------------------------------------------------------------
extern "C" void kernel_launch(void* const* d_in, const int* in_sizes, int n_in,
                              void* d_out, int out_size, void* d_ws, size_t ws_size,
                              hipStream_t stream) {
  const float* q  = (const float*)d_in[0];
  const float* k  = (const float*)d_in[1];
  const float* v  = (const float*)d_in[2];
  const float* Wq = (const float*)d_in[3];
  const float* Wk = (const float*)d_in[4];
  const float* Wv = (const float*)d_in[5];
  const float* Wo = (const float*)d_in[6];

  float* out0 = (float*)d_out;                       // [8,1024,1024]
  float* attn = out0 + (size_t)8 * 1024 * 1024;      // [8,1024,16,1024]

  char* ws = (char*)d_ws;                            // 49 MB used
  __hip_bfloat16* qs    = (__hip_bfloat16*)(ws);                     // 16 MB
  __hip_bfloat16* ksbuf = (__hip_bfloat16*)(ws + (16u << 20));       // 16 MB
  __hip_bfloat16* vsT   = (__hip_bfloat16*)(ws + (32u << 20));       //  1 MB
  __hip_bfloat16* heads = (__hip_bfloat16*)(ws + (33u << 20));       // 16 MB

  dim3 blk(256);
  proj_qk_kernel<<<dim3(64, 16), blk, 0, stream>>>(q, k, Wq, Wk, qs, ksbuf);
  proj_v_kernel<<<dim3(64), blk, 0, stream>>>(v, Wv, vsT);
  attn_kernel<<<dim3(16, 16, 8), blk, 0, stream>>>(qs, ksbuf, vsT, attn, heads);
  out_kernel<<<dim3(512), blk, 0, stream>>>(heads, Wo, out0);
}

// Round 3
// 503.826 us; speedup vs baseline: 1.0919x; 1.0919x over previous
//
#include <hip/hip_runtime.h>
#include <hip/hip_bf16.h>

// ---------------------------------------------------------------------------
// InterpretableMultiHeadAttention  (B=8, S=1024, D=1024, H=16, dk=64)
//   outputs [B,S,D] fp32 ; attn [B,Sq,H,Sk] fp32  (concatenated in d_out)
// Pipeline:
//   1) proj_qk : qs = (q @ Wq^T)/8, ks = k @ Wk^T   (bf16, [b,s,(h,e)] layout)
//   2) proj_v  : vsT = (v @ Wv^T)^T                 (bf16, [b][e][t] layout)
//   3) attn    : 2-pass softmax, SWAPPED QK^T (mfma(K,Q) -> P^T fragments):
//                per-lane float4 NT attn stores, 2-shuffle row reduce,
//                PV via MFMA, heads -> ws (bf16)
//   4) out     : outputs = mean_h(heads) @ Wo^T     (VALU)
// All f32->bf16 conversions are round-to-nearest-even (truncation's coherent
// bias compounded to ~-1.2% on scores -> 6e-3 attn error; RNE kills it).
// ---------------------------------------------------------------------------

typedef __attribute__((ext_vector_type(4))) float f32x4;
typedef __attribute__((ext_vector_type(8))) short bf16x8;
typedef __attribute__((ext_vector_type(2))) unsigned int uint2v;

#define MFMA16(a, b, c) __builtin_amdgcn_mfma_f32_16x16x32_bf16((a), (b), (c), 0, 0, 0)

__device__ __forceinline__ unsigned int rne16(float f) {
  unsigned int u = __float_as_uint(f);
  return u + 0x7fffu + ((u >> 16) & 1u);   // round-to-nearest-even in bit 16
}
__device__ __forceinline__ unsigned int pack2bf(float a, float b) {
  return (rne16(a) >> 16) | (rne16(b) & 0xffff0000u);
}
__device__ __forceinline__ short f2bf(float f) {
  return (short)(rne16(f) >> 16);
}
__device__ __forceinline__ float bf2f(short s) {
  return __uint_as_float(((unsigned int)(unsigned short)s) << 16);
}

// ---------------------------------------------------------------------------
// Kernel 1: fused Q/K projection.  A [8192,1024] f32, W [1024,1024] f32 (B^T
// layout, i.e. [out,in]), C [8192,1024] bf16.  grid = (64, 16): y<8 -> Q, else K.
// ---------------------------------------------------------------------------
__global__ __launch_bounds__(256) void proj_qk_kernel(
    const float* __restrict__ qin, const float* __restrict__ kin,
    const float* __restrict__ Wq, const float* __restrict__ Wk,
    __hip_bfloat16* __restrict__ qs, __hip_bfloat16* __restrict__ ks)
{
  const int K = 1024, N = 1024;
  __shared__ short a_lds[128][40];   // padded stride 40 (80B) -> ~2-way banks
  __shared__ short b_lds[128][40];
  const int tid  = threadIdx.x;
  const int lane = tid & 63, wid = tid >> 6;
  const int g = lane >> 4, r = lane & 15;
  const bool isK = blockIdx.y >= 8;
  const float* A = isK ? kin : qin;
  const float* W = isK ? Wk : Wq;
  __hip_bfloat16* C = isK ? ks : qs;
  const float scale = isK ? 1.0f : 0.125f;   // 1/sqrt(dk)=1/8 folded into qs
  const int m0 = blockIdx.x * 128;
  const int n0 = (blockIdx.y & 7) * 128;
  const int wm = (wid >> 1) * 64, wn = (wid & 1) * 64;
  const int lrow = tid >> 3, lcol = (tid & 7) * 4;

  f32x4 acc[4][4];
#pragma unroll
  for (int i = 0; i < 4; ++i)
#pragma unroll
    for (int j = 0; j < 4; ++j) acc[i][j] = (f32x4){0.f, 0.f, 0.f, 0.f};

  for (int k0 = 0; k0 < K; k0 += 32) {
    float4 av[4], wv[4];
#pragma unroll
    for (int p = 0; p < 4; ++p) {
      av[p] = *(const float4*)&A[(m0 + lrow + p * 32) * K + k0 + lcol];
      wv[p] = *(const float4*)&W[(n0 + lrow + p * 32) * K + k0 + lcol];
    }
    __syncthreads();
#pragma unroll
    for (int p = 0; p < 4; ++p) {
      uint2v ua = {pack2bf(av[p].x, av[p].y), pack2bf(av[p].z, av[p].w)};
      uint2v uw = {pack2bf(wv[p].x, wv[p].y), pack2bf(wv[p].z, wv[p].w)};
      *(uint2v*)&a_lds[lrow + p * 32][lcol] = ua;
      *(uint2v*)&b_lds[lrow + p * 32][lcol] = uw;
    }
    __syncthreads();
    bf16x8 af[4], bf[4];
#pragma unroll
    for (int t = 0; t < 4; ++t) {
      af[t] = *(bf16x8*)&a_lds[wm + t * 16 + r][g * 8];
      bf[t] = *(bf16x8*)&b_lds[wn + t * 16 + r][g * 8];
    }
#pragma unroll
    for (int mt = 0; mt < 4; ++mt)
#pragma unroll
      for (int nt = 0; nt < 4; ++nt)
        acc[mt][nt] = MFMA16(af[mt], bf[nt], acc[mt][nt]);
  }

#pragma unroll
  for (int mt = 0; mt < 4; ++mt)
#pragma unroll
    for (int nt = 0; nt < 4; ++nt) {
      const int n = n0 + wn + nt * 16 + r;
#pragma unroll
      for (int j = 0; j < 4; ++j) {
        const int m = m0 + wm + mt * 16 + 4 * g + j;
        C[m * N + n] = __float2bfloat16(acc[mt][nt][j] * scale);
      }
    }
}

// ---------------------------------------------------------------------------
// Kernel 2: V projection, output TRANSPOSED per batch: vsT[b][e][t] bf16.
// M=8192 (b,t), N=64, K=1024.  grid = 64.
// ---------------------------------------------------------------------------
__global__ __launch_bounds__(256) void proj_v_kernel(
    const float* __restrict__ vin, const float* __restrict__ Wv,
    __hip_bfloat16* __restrict__ vsT)
{
  const int K = 1024;
  __shared__ short a_lds[128][40];
  __shared__ short b_lds[64][40];
  const int tid  = threadIdx.x;
  const int lane = tid & 63, wid = tid >> 6;
  const int g = lane >> 4, r = lane & 15;
  const int m0 = blockIdx.x * 128;
  const int wm = wid * 32;
  const int lrow = tid >> 3, lcol = (tid & 7) * 4;

  f32x4 acc[2][4];
#pragma unroll
  for (int i = 0; i < 2; ++i)
#pragma unroll
    for (int j = 0; j < 4; ++j) acc[i][j] = (f32x4){0.f, 0.f, 0.f, 0.f};

  for (int k0 = 0; k0 < K; k0 += 32) {
    float4 av[4], wv2[2];
#pragma unroll
    for (int p = 0; p < 4; ++p)
      av[p] = *(const float4*)&vin[(m0 + lrow + p * 32) * K + k0 + lcol];
#pragma unroll
    for (int p = 0; p < 2; ++p)
      wv2[p] = *(const float4*)&Wv[(lrow + p * 32) * K + k0 + lcol];
    __syncthreads();
#pragma unroll
    for (int p = 0; p < 4; ++p) {
      uint2v ua = {pack2bf(av[p].x, av[p].y), pack2bf(av[p].z, av[p].w)};
      *(uint2v*)&a_lds[lrow + p * 32][lcol] = ua;
    }
#pragma unroll
    for (int p = 0; p < 2; ++p) {
      uint2v uw = {pack2bf(wv2[p].x, wv2[p].y), pack2bf(wv2[p].z, wv2[p].w)};
      *(uint2v*)&b_lds[lrow + p * 32][lcol] = uw;
    }
    __syncthreads();
    bf16x8 af[2], bf[4];
#pragma unroll
    for (int t = 0; t < 2; ++t) af[t] = *(bf16x8*)&a_lds[wm + t * 16 + r][g * 8];
#pragma unroll
    for (int t = 0; t < 4; ++t) bf[t] = *(bf16x8*)&b_lds[t * 16 + r][g * 8];
#pragma unroll
    for (int mt = 0; mt < 2; ++mt)
#pragma unroll
      for (int nt = 0; nt < 4; ++nt)
        acc[mt][nt] = MFMA16(af[mt], bf[nt], acc[mt][nt]);
  }

#pragma unroll
  for (int mt = 0; mt < 2; ++mt)
#pragma unroll
    for (int nt = 0; nt < 4; ++nt) {
      const int e = nt * 16 + r;
#pragma unroll
      for (int j = 0; j < 4; ++j) {
        const int m = m0 + wm + mt * 16 + 4 * g + j;
        const int b = m >> 10, t = m & 1023;
        vsT[b * 65536 + e * 1024 + t] = __float2bfloat16(acc[mt][nt][j]);
      }
    }
}

// ---------------------------------------------------------------------------
// Kernel 3: fused attention, SWAPPED QK^T.  grid = (S/64=16, H=16, B=8),
// 4 waves, each wave owns 16 query rows.
//   mfma(K,Q): out col = query = r, rows = key t = 4g+j  ->  per-lane 4
//   CONTIGUOUS Sk entries of one attn row: float4 NT store; row-sum reduce
//   is 2 shuffles (xor 16/32).  P staged to per-wave LDS as packed bf16 for
//   the PV A-fragment.  A- and B-fragment lane maps are identical, so the
//   operand swap needs no load changes.
// ---------------------------------------------------------------------------
__global__ __launch_bounds__(256) void attn_kernel(
    const __hip_bfloat16* __restrict__ qs_, const __hip_bfloat16* __restrict__ ks_,
    const __hip_bfloat16* __restrict__ vsT_, float* __restrict__ attn_out,
    __hip_bfloat16* __restrict__ heads_)
{
  const int S = 1024, H = 16;
  const int tid = threadIdx.x, lane = tid & 63, wid = tid >> 6;
  const int g = lane >> 4, r = lane & 15;
  const int qb = blockIdx.x, h = blockIdx.y, b = blockIdx.z;
  const int bh = b * H + h;
  const int qrow = qb * 64 + wid * 16;
  __shared__ short p_lds[4][16][40];   // per-wave P^T staging (stride 80B)

  const short* qsp = (const short*)qs_;
  const short* ksp = (const short*)ks_;
  const short* vsp = (const short*)vsT_;
  short* headsp = (short*)heads_;

  const int qidx = (b * S + qrow + r) * 1024 + h * 64;
  const bf16x8 qf0 = *(const bf16x8*)&qsp[qidx + g * 8];
  const bf16x8 qf1 = *(const bf16x8*)&qsp[qidx + 32 + g * 8];
  const int kbase = (b * S + r) * 1024 + h * 64 + g * 8;

  // ---- pass 1: per-query sum of exp(scores), 64 keys/iter (8 loads in flight)
  float ls0 = 0.f, ls1 = 0.f, ls2 = 0.f, ls3 = 0.f;
  for (int t0 = 0; t0 < S; t0 += 64) {
    bf16x8 kf[8];
#pragma unroll
    for (int u = 0; u < 4; ++u) {
      kf[2 * u]     = *(const bf16x8*)&ksp[kbase + (t0 + 16 * u) * 1024];
      kf[2 * u + 1] = *(const bf16x8*)&ksp[kbase + (t0 + 16 * u) * 1024 + 32];
    }
    float lp[4];
#pragma unroll
    for (int u = 0; u < 4; ++u) {
      f32x4 s = (f32x4){0.f, 0.f, 0.f, 0.f};
      s = MFMA16(kf[2 * u], qf0, s);
      s = MFMA16(kf[2 * u + 1], qf1, s);
      lp[u] = (__expf(s[0]) + __expf(s[1])) + (__expf(s[2]) + __expf(s[3]));
    }
    ls0 += lp[0]; ls1 += lp[1]; ls2 += lp[2]; ls3 += lp[3];
  }
  float ls = (ls0 + ls1) + (ls2 + ls3);
  ls += __shfl_xor(ls, 16);
  ls += __shfl_xor(ls, 32);
  const float inv = 1.f / ls;

  // ---- pass 2: recompute scores, NT-write attn (float4), PV ----
  f32x4 hacc[4];
#pragma unroll
  for (int i = 0; i < 4; ++i) hacc[i] = (f32x4){0.f, 0.f, 0.f, 0.f};

  const int arow = ((b * S + qrow + r) * H + h) * S;   // attn row for query r
  const int vbase = b * 65536 + r * 1024 + g * 8;

  for (int tc = 0; tc < S; tc += 32) {
    bf16x8 vf[4], kf[4];
#pragma unroll
    for (int nt = 0; nt < 4; ++nt)
      vf[nt] = *(const bf16x8*)&vsp[vbase + nt * 16384 + tc];
#pragma unroll
    for (int sub = 0; sub < 2; ++sub) {
      kf[2 * sub]     = *(const bf16x8*)&ksp[kbase + (tc + 16 * sub) * 1024];
      kf[2 * sub + 1] = *(const bf16x8*)&ksp[kbase + (tc + 16 * sub) * 1024 + 32];
    }
#pragma unroll
    for (int sub = 0; sub < 2; ++sub) {
      f32x4 s = (f32x4){0.f, 0.f, 0.f, 0.f};
      s = MFMA16(kf[2 * sub], qf0, s);
      s = MFMA16(kf[2 * sub + 1], qf1, s);
      f32x4 p;
      p[0] = __expf(s[0]) * inv;
      p[1] = __expf(s[1]) * inv;
      p[2] = __expf(s[2]) * inv;
      p[3] = __expf(s[3]) * inv;
      // attn row (b, qrow+r, h): cols tc+sub*16+4g .. +3  (contiguous 16B)
      __builtin_nontemporal_store(p, (f32x4*)&attn_out[arow + tc + sub * 16 + 4 * g]);
      uint2v pk = {pack2bf(p[0], p[1]), pack2bf(p[2], p[3])};
      *(uint2v*)&p_lds[wid][r][sub * 16 + 4 * g] = pk;
    }
    // cross-lane LDS hazard (within wave): drain DS queue before reading back
    asm volatile("s_waitcnt lgkmcnt(0)" ::: "memory");
    const bf16x8 pa = *(bf16x8*)&p_lds[wid][r][g * 8];
#pragma unroll
    for (int nt = 0; nt < 4; ++nt)
      hacc[nt] = MFMA16(pa, vf[nt], hacc[nt]);
  }

#pragma unroll
  for (int nt = 0; nt < 4; ++nt)
#pragma unroll
    for (int j = 0; j < 4; ++j)
      headsp[(bh * S + qrow + 4 * g + j) * 64 + nt * 16 + r] =
          f2bf(hacc[nt][j]);
}

// ---------------------------------------------------------------------------
// Kernel 4: outputs = mean_h(heads) @ Wo^T.  grid = 512, 16 rows per block.
// ---------------------------------------------------------------------------
__global__ __launch_bounds__(256) void out_kernel(
    const __hip_bfloat16* __restrict__ heads_, const float* __restrict__ Wo,
    float* __restrict__ out)
{
  __shared__ float hm[16][64];
  const int tid = threadIdx.x;
  const int m0 = blockIdx.x * 16;
  const short* headsp = (const short*)heads_;

  {
    const int row = tid >> 4, e4 = (tid & 15) * 4;
    const int m = m0 + row, b = m >> 10, s = m & 1023;
    float a0 = 0.f, a1 = 0.f, a2 = 0.f, a3 = 0.f;
    for (int hh = 0; hh < 16; ++hh) {
      typedef __attribute__((ext_vector_type(4))) short short4v;
      const short4v hv =
          *(const short4v*)&headsp[((b * 16 + hh) * 1024 + s) * 64 + e4];
      a0 += bf2f(hv[0]); a1 += bf2f(hv[1]); a2 += bf2f(hv[2]); a3 += bf2f(hv[3]);
    }
    const float sc = 1.f / 16.f;
    hm[row][e4 + 0] = a0 * sc; hm[row][e4 + 1] = a1 * sc;
    hm[row][e4 + 2] = a2 * sc; hm[row][e4 + 3] = a3 * sc;
  }
  __syncthreads();

  for (int c = 0; c < 4; ++c) {
    const int d = c * 256 + tid;
    float4 wo4[16];
#pragma unroll
    for (int i = 0; i < 16; ++i) wo4[i] = *(const float4*)&Wo[d * 64 + i * 4];
    for (int row = 0; row < 16; ++row) {
      float a = 0.f;
#pragma unroll
      for (int i = 0; i < 16; ++i) {
        const float4 h4 = *(const float4*)&hm[row][i * 4];
        a += h4.x * wo4[i].x + h4.y * wo4[i].y + h4.z * wo4[i].z + h4.w * wo4[i].w;
      }
      out[(m0 + row) * 1024 + d] = a;
    }
  }
}

// ---------------------------------------------------------------------------
extern "C" void kernel_launch(void* const* d_in, const int* in_sizes, int n_in,
                              void* d_out, int out_size, void* d_ws, size_t ws_size,
                              hipStream_t stream) {
  const float* q  = (const float*)d_in[0];
  const float* k  = (const float*)d_in[1];
  const float* v  = (const float*)d_in[2];
  const float* Wq = (const float*)d_in[3];
  const float* Wk = (const float*)d_in[4];
  const float* Wv = (const float*)d_in[5];
  const float* Wo = (const float*)d_in[6];

  float* out0 = (float*)d_out;                       // [8,1024,1024]
  float* attn = out0 + (size_t)8 * 1024 * 1024;      // [8,1024,16,1024]

  char* ws = (char*)d_ws;                            // 49 MB used
  __hip_bfloat16* qs    = (__hip_bfloat16*)(ws);                     // 16 MB
  __hip_bfloat16* ksbuf = (__hip_bfloat16*)(ws + (16u << 20));       // 16 MB
  __hip_bfloat16* vsT   = (__hip_bfloat16*)(ws + (32u << 20));       //  1 MB
  __hip_bfloat16* heads = (__hip_bfloat16*)(ws + (33u << 20));       // 16 MB

  dim3 blk(256);
  proj_qk_kernel<<<dim3(64, 16), blk, 0, stream>>>(q, k, Wq, Wk, qs, ksbuf);
  proj_v_kernel<<<dim3(64), blk, 0, stream>>>(v, Wv, vsT);
  attn_kernel<<<dim3(16, 16, 8), blk, 0, stream>>>(qs, ksbuf, vsT, attn, heads);
  out_kernel<<<dim3(512), blk, 0, stream>>>(heads, Wo, out0);
}